// Round 10
// baseline (530.223 us; speedup 1.0000x reference)
//
#include <hip/hip_runtime.h>
#include <hip/hip_bf16.h>

#define NN 20000
#define MPAD 20096          // 157 * 128
#define EE 160000
#define ETOT 180000         // edges + self loops
#define HH 8
#define DD 512
#define CC 64
#define GG 128
#define OUTD 128

typedef __bf16 bf16x8 __attribute__((ext_vector_type(8)));
typedef unsigned short u16x8 __attribute__((ext_vector_type(8)));
typedef float f32x4 __attribute__((ext_vector_type(4)));

__device__ __forceinline__ float bf2f(unsigned short u) {
    unsigned int x = ((unsigned int)u) << 16;
    return __builtin_bit_cast(float, x);
}
__device__ __forceinline__ unsigned short f2bf(float f) {
    unsigned int x = __builtin_bit_cast(unsigned int, f);
    unsigned int r = (x + 0x7fff + ((x >> 16) & 1)) >> 16;
    return (unsigned short)r;
}

// ---------------- CSR build ----------------

__global__ void k_degree(const int* __restrict__ ei, int* __restrict__ deg) {
    int e = blockIdx.x * blockDim.x + threadIdx.x;
    if (e >= ETOT) return;
    int dst = (e < EE) ? ei[EE + e] : (e - EE);
    atomicAdd(&deg[dst], 1);
}

__global__ __launch_bounds__(1024) void k_scan(const int* __restrict__ deg,
                                               int* __restrict__ rowptr) {
    __shared__ int part[1024];
    const int n = NN;
    const int per = (n + 1023) / 1024;
    int base = threadIdx.x * per;
    int s = 0;
    for (int i = 0; i < per; i++) {
        int idx = base + i;
        if (idx < n) s += deg[idx];
    }
    part[threadIdx.x] = s;
    __syncthreads();
    for (int off = 1; off < 1024; off <<= 1) {
        int v = 0;
        if ((int)threadIdx.x >= off) v = part[threadIdx.x - off];
        __syncthreads();
        part[threadIdx.x] += v;
        __syncthreads();
    }
    int run = (threadIdx.x == 0) ? 0 : part[threadIdx.x - 1];
    for (int i = 0; i < per; i++) {
        int idx = base + i;
        if (idx < n) { rowptr[idx] = run; run += deg[idx]; }
    }
    if (threadIdx.x == 1023) rowptr[n] = part[1023];
}

__global__ void k_scatter(const int* __restrict__ ei, int* __restrict__ wp,
                          int* __restrict__ csr) {
    int e = blockIdx.x * blockDim.x + threadIdx.x;
    if (e >= ETOT) return;
    int src, dst;
    if (e < EE) { src = ei[e]; dst = ei[EE + e]; }
    else        { src = e - EE; dst = e - EE; }
    int pos = atomicAdd(&wp[dst], 1);
    csr[pos] = src;
}

// ---------------- f32 -> bf16 cast (with zero pad rows) ----------------

__global__ __launch_bounds__(256) void k_cast_x(const float* __restrict__ x,
                                                unsigned short* __restrict__ xb) {
    long long i = (long long)(blockIdx.x * 256 + threadIdx.x) * 4;
    if (i >= (long long)MPAD * DD) return;
    ushort4 o;
    if (i < (long long)NN * DD) {
        float4 v = *reinterpret_cast<const float4*>(&x[i]);
        o.x = f2bf(v.x); o.y = f2bf(v.y); o.z = f2bf(v.z); o.w = f2bf(v.w);
    } else {
        o = make_ushort4(0, 0, 0, 0);
    }
    *reinterpret_cast<ushort4*>(&xb[i]) = o;
}

// ---------------- W transpose + cast: Wt[n][k] = bf16(W[k][n]) ----------------

__global__ __launch_bounds__(256) void k_wt(const float* __restrict__ W,
                                            unsigned short* __restrict__ Wt) {
    __shared__ float t[32][33];
    int tx = threadIdx.x, ty = threadIdx.y;
    int bk = blockIdx.x * 32, bn = blockIdx.y * 32;
#pragma unroll
    for (int j = 0; j < 4; j++)
        t[ty + j * 8][tx] = W[(bk + ty + j * 8) * DD + bn + tx];
    __syncthreads();
#pragma unroll
    for (int j = 0; j < 4; j++)
        Wt[(bn + ty + j * 8) * DD + bk + tx] = f2bf(t[tx][ty + j * 8]);
}

// ---------------- bf16 MFMA GEMM (m97 structure, 128x128 tile, BK=32) ----------------

__global__ __launch_bounds__(256) void k_gemm(const unsigned short* __restrict__ A,
                                              const unsigned short* __restrict__ Bt,
                                              unsigned short* __restrict__ C) {
    __shared__ alignas(16) unsigned short As[128 * 32];
    __shared__ alignas(16) unsigned short Bs[128 * 32];
    int tid = threadIdx.x;
    int lane = tid & 63, wv = tid >> 6;
    int row0 = blockIdx.x * 128, col0 = blockIdx.y * 128;
    int wr = (wv >> 1) * 64, wc = (wv & 1) * 64;
    f32x4 acc[4][4] = {};
    int srow = lane >> 2;
    int sel = (lane & 3) * 8;

    for (int k0 = 0; k0 < DD; k0 += 32) {
#pragma unroll
        for (int i = 0; i < 2; i++) {
            int tr = wv * 32 + i * 16 + srow;
            __builtin_amdgcn_global_load_lds(
                (const __attribute__((address_space(1))) unsigned int*)&A[(size_t)(row0 + tr) * DD + k0 + sel],
                (__attribute__((address_space(3))) unsigned int*)&As[(wv * 32 + i * 16) * 32],
                16, 0, 0);
            __builtin_amdgcn_global_load_lds(
                (const __attribute__((address_space(1))) unsigned int*)&Bt[(size_t)(col0 + tr) * DD + k0 + sel],
                (__attribute__((address_space(3))) unsigned int*)&Bs[(wv * 32 + i * 16) * 32],
                16, 0, 0);
        }
        __syncthreads();
        bf16x8 af[4], bfv[4];
        int rsel = lane & 15, g = (lane >> 4) * 8;
#pragma unroll
        for (int m = 0; m < 4; m++)
            af[m] = *reinterpret_cast<const bf16x8*>(&As[(wr + m * 16 + rsel) * 32 + g]);
#pragma unroll
        for (int n2 = 0; n2 < 4; n2++)
            bfv[n2] = *reinterpret_cast<const bf16x8*>(&Bs[(wc + n2 * 16 + rsel) * 32 + g]);
#pragma unroll
        for (int m = 0; m < 4; m++)
#pragma unroll
            for (int n2 = 0; n2 < 4; n2++)
                acc[m][n2] = __builtin_amdgcn_mfma_f32_16x16x32_bf16(af[m], bfv[n2], acc[m][n2], 0, 0, 0);
        __syncthreads();
    }

    int crow = (lane >> 4) * 4, ccol = lane & 15;
#pragma unroll
    for (int m = 0; m < 4; m++) {
#pragma unroll
        for (int r = 0; r < 4; r++) {
            int row = row0 + wr + m * 16 + crow + r;
            if (row < NN) {
#pragma unroll
                for (int n2 = 0; n2 < 4; n2++)
                    C[(size_t)row * DD + col0 + wc + n2 * 16 + ccol] = f2bf(acc[m][n2][r]);
            }
        }
    }
}

// ---------------- attention scores ----------------

__global__ __launch_bounds__(256) void k_scores(const unsigned short* __restrict__ h,
                                                const float* __restrict__ a_s,
                                                const float* __restrict__ a_d,
                                                float* __restrict__ es,
                                                float* __restrict__ ed) {
    int wid = (blockIdx.x * 256 + threadIdx.x) >> 6;
    int lane = threadIdx.x & 63;
    if (wid >= NN * HH) return;
    int n = wid >> 3, hh = wid & 7;
    float v = bf2f(h[(size_t)n * DD + hh * CC + lane]);
    float ps = v * a_s[hh * CC + lane];
    float pd = v * a_d[hh * CC + lane];
#pragma unroll
    for (int off = 32; off > 0; off >>= 1) {
        ps += __shfl_down(ps, off);
        pd += __shfl_down(pd, off);
    }
    if (lane == 0) { es[wid] = ps; ed[wid] = pd; }
}

// ---------------- edge softmax: unnormalized p per CSR slot + inverse denom ----------------
// one thread per (node, head)

__global__ __launch_bounds__(256) void k_alpha(const float* __restrict__ es,
                                               const float* __restrict__ ed,
                                               const int* __restrict__ rowptr,
                                               const int* __restrict__ csr,
                                               float* __restrict__ alpha,
                                               float* __restrict__ invden) {
    int id = blockIdx.x * 256 + threadIdx.x;
    if (id >= NN * HH) return;
    int n = id >> 3, hh = id & 7;
    int r0 = rowptr[n], r1 = rowptr[n + 1];
    float edn = ed[id];
    float m = -1e30f;
    for (int j = r0; j < r1; j++) {
        float e = es[csr[j] * 8 + hh] + edn;
        e = (e >= 0.f) ? e : 0.2f * e;
        m = fmaxf(m, e);
    }
    float sum = 0.f;
    for (int j = r0; j < r1; j++) {
        float e = es[csr[j] * 8 + hh] + edn;
        e = (e >= 0.f) ? e : 0.2f * e;
        float pv = __expf(e - m);
        alpha[(size_t)j * 8 + hh] = pv;
        sum += pv;
    }
    invden[id] = 1.f / (sum + 1e-16f);
}

// ---------------- gather-aggregate + bias + LayerNorm + ReLU ----------------
// one wave per node, 4 waves/block, no __syncthreads; lane owns 8 contiguous dims

__global__ __launch_bounds__(256) void k_aggln(const unsigned short* __restrict__ h,
                                               const float* __restrict__ alpha,
                                               const float* __restrict__ invden,
                                               const int* __restrict__ rowptr,
                                               const int* __restrict__ csr,
                                               const float* __restrict__ bias,
                                               const float* __restrict__ gamma,
                                               const float* __restrict__ beta,
                                               unsigned short* __restrict__ xout) {
    int wv = threadIdx.x >> 6, lane = threadIdx.x & 63;
    int n = blockIdx.x * 4 + wv;
    int r0 = rowptr[n], r1 = rowptr[n + 1];
    int head = lane >> 3;
    int d0 = lane * 8;

    float acc[8] = {};
    for (int j = r0; j < r1; j++) {
        int s = csr[j];
        float p = alpha[(size_t)j * 8 + head];
        u16x8 hv = *reinterpret_cast<const u16x8*>(&h[(size_t)s * DD + d0]);
#pragma unroll
        for (int k = 0; k < 8; k++) acc[k] += p * bf2f(hv[k]);
    }

    float inv = invden[n * 8 + head];
    float s1 = 0.f, s2 = 0.f;
#pragma unroll
    for (int k = 0; k < 8; k++) {
        acc[k] = acc[k] * inv + bias[d0 + k];
        s1 += acc[k];
        s2 += acc[k] * acc[k];
    }
#pragma unroll
    for (int off = 1; off < 64; off <<= 1) {
        s1 += __shfl_xor(s1, off);
        s2 += __shfl_xor(s2, off);
    }
    float mu = s1 * (1.f / 512.f);
    float var = s2 * (1.f / 512.f) - mu * mu;
    float rs = rsqrtf(var + 1e-5f);

    u16x8 o;
#pragma unroll
    for (int k = 0; k < 8; k++) {
        float y = (acc[k] - mu) * rs * gamma[d0 + k] + beta[d0 + k];
        o[k] = f2bf(fmaxf(y, 0.f));
    }
    *reinterpret_cast<u16x8*>(&xout[(size_t)n * DD + d0]) = o;
}

// ---------------- pooling + FC ----------------

__global__ void k_gbounds(const int* __restrict__ batch, int* __restrict__ gstart) {
    int g = blockIdx.x * blockDim.x + threadIdx.x;
    if (g > GG) return;
    int lo = 0, hi = NN;
    while (lo < hi) {
        int mid = (lo + hi) >> 1;
        if (batch[mid] < g) lo = mid + 1; else hi = mid;
    }
    gstart[g] = lo;
}

// parallel pooling: grid (GG, 8 node-stripes); partial sums in regs, one atomicAdd per dim
__global__ __launch_bounds__(256) void k_pool1(const unsigned short* __restrict__ x,
                                               const int* __restrict__ gstart,
                                               float* __restrict__ pooled) {
    int g = blockIdx.x, stripe = blockIdx.y, tid = threadIdx.x;
    int s = gstart[g], e = gstart[g + 1];
    float a0 = 0.f, a1 = 0.f;
    for (int n = s + stripe; n < e; n += 8) {
        unsigned int u = *reinterpret_cast<const unsigned int*>(&x[(size_t)n * DD + tid * 2]);
        a0 += bf2f((unsigned short)(u & 0xffff));
        a1 += bf2f((unsigned short)(u >> 16));
    }
    atomicAdd(&pooled[g * DD + tid * 2], a0);
    atomicAdd(&pooled[g * DD + tid * 2 + 1], a1);
}

// FC with mean-divide folded in; 256 threads, split-K=2 via LDS
__global__ __launch_bounds__(256) void k_fc(const float* __restrict__ pooled,
                                            const int* __restrict__ gstart,
                                            const float* __restrict__ Wf,
                                            const float* __restrict__ bf,
                                            float* __restrict__ out) {
    int g = blockIdx.x, tid = threadIdx.x;
    int o = tid & 127, half = tid >> 7;
    __shared__ float row[DD];
    __shared__ float part[256];
    float inv = 1.f / fmaxf((float)(gstart[g + 1] - gstart[g]), 1.f);
    for (int i = tid; i < DD; i += 256) row[i] = pooled[g * DD + i] * inv;
    __syncthreads();
    float acc = 0.f;
    int dbase = half * 256;
    for (int d = dbase; d < dbase + 256; d++) acc += row[d] * Wf[d * OUTD + o];
    part[tid] = acc;
    __syncthreads();
    if (half == 0) out[g * OUTD + o] = part[o] + part[o + 128] + bf[o];
}

// ---------------- launch ----------------

extern "C" void kernel_launch(void* const* d_in, const int* in_sizes, int n_in,
                              void* d_out, int out_size, void* d_ws, size_t ws_size,
                              hipStream_t stream) {
    const float* x     = (const float*)d_in[0];
    const int*   ei    = (const int*)d_in[1];
    const int*   batch = (const int*)d_in[2];
    const float* W[3]  = {(const float*)d_in[3], (const float*)d_in[9],  (const float*)d_in[15]};
    const float* As_[3] = {(const float*)d_in[4], (const float*)d_in[10], (const float*)d_in[16]};
    const float* Ad_[3] = {(const float*)d_in[5], (const float*)d_in[11], (const float*)d_in[17]};
    const float* Bi[3] = {(const float*)d_in[6], (const float*)d_in[12], (const float*)d_in[18]};
    const float* Ga[3] = {(const float*)d_in[7], (const float*)d_in[13], (const float*)d_in[19]};
    const float* Be[3] = {(const float*)d_in[8], (const float*)d_in[14], (const float*)d_in[20]};
    const float* fcW = (const float*)d_in[21];
    const float* fcb = (const float*)d_in[22];
    float* out = (float*)d_out;

    char* p = (char*)d_ws;
    auto carve = [&](size_t bytes) {
        char* r = p;
        p += (bytes + 255) & ~((size_t)255);
        return r;
    };
    unsigned short* xb0  = (unsigned short*)carve((size_t)MPAD * DD * 2);
    unsigned short* xb1  = (unsigned short*)carve((size_t)MPAD * DD * 2);
    unsigned short* hbuf = (unsigned short*)carve((size_t)MPAD * DD * 2);
    unsigned short* Wt   = (unsigned short*)carve((size_t)DD * DD * 2);
    float* es     = (float*)carve((size_t)NN * HH * 4);
    float* ed     = (float*)carve((size_t)NN * HH * 4);
    float* alpha  = (float*)carve((size_t)ETOT * HH * 4);
    float* invden = (float*)carve((size_t)NN * HH * 4);
    int*   deg    = (int*)carve((size_t)NN * 4);
    int*   rowptr = (int*)carve((size_t)(NN + 1) * 4);
    int*   wp     = (int*)carve((size_t)NN * 4);
    int*   csr    = (int*)carve((size_t)ETOT * 4);
    int*   gstart = (int*)carve((size_t)(GG + 1) * 4);
    float* pooled = (float*)carve((size_t)GG * DD * 4);

    // CSR build
    hipMemsetAsync(deg, 0, (size_t)NN * 4, stream);
    hipMemsetAsync(pooled, 0, (size_t)GG * DD * 4, stream);
    k_degree<<<(ETOT + 255) / 256, 256, 0, stream>>>(ei, deg);
    k_scan<<<1, 1024, 0, stream>>>(deg, rowptr);
    hipMemcpyAsync(wp, rowptr, (size_t)NN * 4, hipMemcpyDeviceToDevice, stream);
    k_scatter<<<(ETOT + 255) / 256, 256, 0, stream>>>(ei, wp, csr);
    k_gbounds<<<1, 256, 0, stream>>>(batch, gstart);

    // zero pad rows of xb1 (xb0's pad is zeroed by k_cast_x)
    hipMemsetAsync(xb1 + (size_t)NN * DD, 0, (size_t)(MPAD - NN) * DD * 2, stream);
    k_cast_x<<<(MPAD * DD / 4 + 255) / 256, 256, 0, stream>>>(x, xb0);

    unsigned short* xin = xb0;
    unsigned short* xnext = xb1;
    for (int l = 0; l < 3; l++) {
        k_wt<<<dim3(16, 16), dim3(32, 8), 0, stream>>>(W[l], Wt);
        k_gemm<<<dim3(MPAD / 128, 4), 256, 0, stream>>>(xin, Wt, hbuf);
        k_scores<<<(NN * HH) / 4, 256, 0, stream>>>(hbuf, As_[l], Ad_[l], es, ed);
        k_alpha<<<(NN * HH + 255) / 256, 256, 0, stream>>>(es, ed, rowptr, csr, alpha, invden);
        k_aggln<<<NN / 4, 256, 0, stream>>>(hbuf, alpha, invden, rowptr, csr,
                                            Bi[l], Ga[l], Be[l], xnext);
        unsigned short* t = xin; xin = xnext; xnext = t;
    }

    // after 3 swaps, final output is in xin
    k_pool1<<<dim3(GG, 8), 256, 0, stream>>>(xin, gstart, pooled);
    k_fc<<<GG, 256, 0, stream>>>(pooled, gstart, fcW, fcb, out);
}

// Round 13
// 476.853 us; speedup vs baseline: 1.1119x; 1.1119x over previous
//
#include <hip/hip_runtime.h>
#include <hip/hip_bf16.h>

#define NN 20000
#define MPAD 20096          // 157 * 128
#define EE 160000
#define ETOT 180000         // edges + self loops
#define HH 8
#define DD 512
#define CC 64
#define GG 128
#define OUTD 128

typedef __bf16 bf16x8 __attribute__((ext_vector_type(8)));
typedef unsigned short u16x8 __attribute__((ext_vector_type(8)));
typedef float f32x4 __attribute__((ext_vector_type(4)));

__device__ __forceinline__ float bf2f(unsigned short u) {
    unsigned int x = ((unsigned int)u) << 16;
    return __builtin_bit_cast(float, x);
}
__device__ __forceinline__ unsigned short f2bf(float f) {
    unsigned int x = __builtin_bit_cast(unsigned int, f);
    unsigned int r = (x + 0x7fff + ((x >> 16) & 1)) >> 16;
    return (unsigned short)r;
}

// ---------------- CSR build ----------------

__global__ void k_degree(const int* __restrict__ ei, int* __restrict__ deg) {
    int e = blockIdx.x * blockDim.x + threadIdx.x;
    if (e >= ETOT) return;
    int dst = (e < EE) ? ei[EE + e] : (e - EE);
    atomicAdd(&deg[dst], 1);
}

__global__ __launch_bounds__(1024) void k_scan(const int* __restrict__ deg,
                                               int* __restrict__ rowptr) {
    __shared__ int part[1024];
    const int n = NN;
    const int per = (n + 1023) / 1024;
    int base = threadIdx.x * per;
    int s = 0;
    for (int i = 0; i < per; i++) {
        int idx = base + i;
        if (idx < n) s += deg[idx];
    }
    part[threadIdx.x] = s;
    __syncthreads();
    for (int off = 1; off < 1024; off <<= 1) {
        int v = 0;
        if ((int)threadIdx.x >= off) v = part[threadIdx.x - off];
        __syncthreads();
        part[threadIdx.x] += v;
        __syncthreads();
    }
    int run = (threadIdx.x == 0) ? 0 : part[threadIdx.x - 1];
    for (int i = 0; i < per; i++) {
        int idx = base + i;
        if (idx < n) { rowptr[idx] = run; run += deg[idx]; }
    }
    if (threadIdx.x == 1023) rowptr[n] = part[1023];
}

__global__ void k_scatter(const int* __restrict__ ei, int* __restrict__ wp,
                          int* __restrict__ csr) {
    int e = blockIdx.x * blockDim.x + threadIdx.x;
    if (e >= ETOT) return;
    int src, dst;
    if (e < EE) { src = ei[e]; dst = ei[EE + e]; }
    else        { src = e - EE; dst = e - EE; }
    int pos = atomicAdd(&wp[dst], 1);
    csr[pos] = src;
}

// ---------------- f32 -> bf16 cast (with zero pad rows) ----------------

__global__ __launch_bounds__(256) void k_cast_x(const float* __restrict__ x,
                                                unsigned short* __restrict__ xb) {
    long long i = (long long)(blockIdx.x * 256 + threadIdx.x) * 4;
    if (i >= (long long)MPAD * DD) return;
    ushort4 o;
    if (i < (long long)NN * DD) {
        float4 v = *reinterpret_cast<const float4*>(&x[i]);
        o.x = f2bf(v.x); o.y = f2bf(v.y); o.z = f2bf(v.z); o.w = f2bf(v.w);
    } else {
        o = make_ushort4(0, 0, 0, 0);
    }
    *reinterpret_cast<ushort4*>(&xb[i]) = o;
}

// ---------------- W transpose + cast: Wt[n][k] = bf16(W[k][n]) ----------------

__global__ __launch_bounds__(256) void k_wt(const float* __restrict__ W,
                                            unsigned short* __restrict__ Wt) {
    __shared__ float t[32][33];
    int tx = threadIdx.x, ty = threadIdx.y;
    int bk = blockIdx.x * 32, bn = blockIdx.y * 32;
#pragma unroll
    for (int j = 0; j < 4; j++)
        t[ty + j * 8][tx] = W[(bk + ty + j * 8) * DD + bn + tx];
    __syncthreads();
#pragma unroll
    for (int j = 0; j < 4; j++)
        Wt[(bn + ty + j * 8) * DD + bk + tx] = f2bf(t[tx][ty + j * 8]);
}

// ---------------- bf16 MFMA GEMM (m97 structure, 128x128 tile, BK=32) ----------------

__global__ __launch_bounds__(256) void k_gemm(const unsigned short* __restrict__ A,
                                              const unsigned short* __restrict__ Bt,
                                              unsigned short* __restrict__ C) {
    __shared__ alignas(16) unsigned short As[128 * 32];
    __shared__ alignas(16) unsigned short Bs[128 * 32];
    int tid = threadIdx.x;
    int lane = tid & 63, wv = tid >> 6;
    int row0 = blockIdx.x * 128, col0 = blockIdx.y * 128;
    int wr = (wv >> 1) * 64, wc = (wv & 1) * 64;
    f32x4 acc[4][4] = {};
    int srow = lane >> 2;
    int sel = (lane & 3) * 8;

    for (int k0 = 0; k0 < DD; k0 += 32) {
#pragma unroll
        for (int i = 0; i < 2; i++) {
            int tr = wv * 32 + i * 16 + srow;
            __builtin_amdgcn_global_load_lds(
                (const __attribute__((address_space(1))) unsigned int*)&A[(size_t)(row0 + tr) * DD + k0 + sel],
                (__attribute__((address_space(3))) unsigned int*)&As[(wv * 32 + i * 16) * 32],
                16, 0, 0);
            __builtin_amdgcn_global_load_lds(
                (const __attribute__((address_space(1))) unsigned int*)&Bt[(size_t)(col0 + tr) * DD + k0 + sel],
                (__attribute__((address_space(3))) unsigned int*)&Bs[(wv * 32 + i * 16) * 32],
                16, 0, 0);
        }
        __syncthreads();
        bf16x8 af[4], bfv[4];
        int rsel = lane & 15, g = (lane >> 4) * 8;
#pragma unroll
        for (int m = 0; m < 4; m++)
            af[m] = *reinterpret_cast<const bf16x8*>(&As[(wr + m * 16 + rsel) * 32 + g]);
#pragma unroll
        for (int n2 = 0; n2 < 4; n2++)
            bfv[n2] = *reinterpret_cast<const bf16x8*>(&Bs[(wc + n2 * 16 + rsel) * 32 + g]);
#pragma unroll
        for (int m = 0; m < 4; m++)
#pragma unroll
            for (int n2 = 0; n2 < 4; n2++)
                acc[m][n2] = __builtin_amdgcn_mfma_f32_16x16x32_bf16(af[m], bfv[n2], acc[m][n2], 0, 0, 0);
        __syncthreads();
    }

    int crow = (lane >> 4) * 4, ccol = lane & 15;
#pragma unroll
    for (int m = 0; m < 4; m++) {
#pragma unroll
        for (int r = 0; r < 4; r++) {
            int row = row0 + wr + m * 16 + crow + r;
            if (row < NN) {
#pragma unroll
                for (int n2 = 0; n2 < 4; n2++)
                    C[(size_t)row * DD + col0 + wc + n2 * 16 + ccol] = f2bf(acc[m][n2][r]);
            }
        }
    }
}

// ---------------- attention scores ----------------

__global__ __launch_bounds__(256) void k_scores(const unsigned short* __restrict__ h,
                                                const float* __restrict__ a_s,
                                                const float* __restrict__ a_d,
                                                float* __restrict__ es,
                                                float* __restrict__ ed) {
    int wid = (blockIdx.x * 256 + threadIdx.x) >> 6;
    int lane = threadIdx.x & 63;
    if (wid >= NN * HH) return;
    int n = wid >> 3, hh = wid & 7;
    float v = bf2f(h[(size_t)n * DD + hh * CC + lane]);
    float ps = v * a_s[hh * CC + lane];
    float pd = v * a_d[hh * CC + lane];
#pragma unroll
    for (int off = 32; off > 0; off >>= 1) {
        ps += __shfl_down(ps, off);
        pd += __shfl_down(pd, off);
    }
    if (lane == 0) { es[wid] = ps; ed[wid] = pd; }
}

// ---------------- edge softmax: unnormalized p per CSR slot + inverse denom ----------------
// one thread per (node, head)

__global__ __launch_bounds__(256) void k_alpha(const float* __restrict__ es,
                                               const float* __restrict__ ed,
                                               const int* __restrict__ rowptr,
                                               const int* __restrict__ csr,
                                               float* __restrict__ alpha,
                                               float* __restrict__ invden) {
    int id = blockIdx.x * 256 + threadIdx.x;
    if (id >= NN * HH) return;
    int n = id >> 3, hh = id & 7;
    int r0 = rowptr[n], r1 = rowptr[n + 1];
    float edn = ed[id];
    float m = -1e30f;
    for (int j = r0; j < r1; j++) {
        float e = es[csr[j] * 8 + hh] + edn;
        e = (e >= 0.f) ? e : 0.2f * e;
        m = fmaxf(m, e);
    }
    float sum = 0.f;
    for (int j = r0; j < r1; j++) {
        float e = es[csr[j] * 8 + hh] + edn;
        e = (e >= 0.f) ? e : 0.2f * e;
        float pv = __expf(e - m);
        alpha[(size_t)j * 8 + hh] = pv;
        sum += pv;
    }
    invden[id] = 1.f / (sum + 1e-16f);
}

// ---------------- gather-aggregate + bias + LayerNorm + ReLU ----------------
// one wave per node, 4 waves/block, no __syncthreads; lane owns 8 contiguous dims

__global__ __launch_bounds__(256) void k_aggln(const unsigned short* __restrict__ h,
                                               const float* __restrict__ alpha,
                                               const float* __restrict__ invden,
                                               const int* __restrict__ rowptr,
                                               const int* __restrict__ csr,
                                               const float* __restrict__ bias,
                                               const float* __restrict__ gamma,
                                               const float* __restrict__ beta,
                                               unsigned short* __restrict__ xout) {
    int wv = threadIdx.x >> 6, lane = threadIdx.x & 63;
    int n = blockIdx.x * 4 + wv;
    int r0 = rowptr[n], r1 = rowptr[n + 1];
    int head = lane >> 3;
    int d0 = lane * 8;

    float acc[8] = {};
    for (int j = r0; j < r1; j++) {
        int s = csr[j];
        float p = alpha[(size_t)j * 8 + head];
        u16x8 hv = *reinterpret_cast<const u16x8*>(&h[(size_t)s * DD + d0]);
#pragma unroll
        for (int k = 0; k < 8; k++) acc[k] += p * bf2f(hv[k]);
    }

    float inv = invden[n * 8 + head];
    float s1 = 0.f, s2 = 0.f;
#pragma unroll
    for (int k = 0; k < 8; k++) {
        acc[k] = acc[k] * inv + bias[d0 + k];
        s1 += acc[k];
        s2 += acc[k] * acc[k];
    }
#pragma unroll
    for (int off = 1; off < 64; off <<= 1) {
        s1 += __shfl_xor(s1, off);
        s2 += __shfl_xor(s2, off);
    }
    float mu = s1 * (1.f / 512.f);
    float var = s2 * (1.f / 512.f) - mu * mu;
    float rs = rsqrtf(var + 1e-5f);

    u16x8 o;
#pragma unroll
    for (int k = 0; k < 8; k++) {
        float y = (acc[k] - mu) * rs * gamma[d0 + k] + beta[d0 + k];
        o[k] = f2bf(fmaxf(y, 0.f));
    }
    *reinterpret_cast<u16x8*>(&xout[(size_t)n * DD + d0]) = o;
}

// ---------------- pooling + FC ----------------

__global__ void k_gbounds(const int* __restrict__ batch, int* __restrict__ gstart) {
    int g = blockIdx.x * blockDim.x + threadIdx.x;
    if (g > GG) return;
    int lo = 0, hi = NN;
    while (lo < hi) {
        int mid = (lo + hi) >> 1;
        if (batch[mid] < g) lo = mid + 1; else hi = mid;
    }
    gstart[g] = lo;
}

// parallel pooling: grid (GG, 8 node-stripes); partial sums in regs, one atomicAdd per dim
__global__ __launch_bounds__(256) void k_pool1(const unsigned short* __restrict__ x,
                                               const int* __restrict__ gstart,
                                               float* __restrict__ pooled) {
    int g = blockIdx.x, stripe = blockIdx.y, tid = threadIdx.x;
    int s = gstart[g], e = gstart[g + 1];
    float a0 = 0.f, a1 = 0.f;
    for (int n = s + stripe; n < e; n += 8) {
        unsigned int u = *reinterpret_cast<const unsigned int*>(&x[(size_t)n * DD + tid * 2]);
        a0 += bf2f((unsigned short)(u & 0xffff));
        a1 += bf2f((unsigned short)(u >> 16));
    }
    atomicAdd(&pooled[g * DD + tid * 2], a0);
    atomicAdd(&pooled[g * DD + tid * 2 + 1], a1);
}

// FC: one thread per (g, o) output; 4 independent FMA chains; mean-divide folded in
__global__ __launch_bounds__(256) void k_fc(const float* __restrict__ pooled,
                                            const int* __restrict__ gstart,
                                            const float* __restrict__ Wf,
                                            const float* __restrict__ bf,
                                            float* __restrict__ out) {
    int idx = blockIdx.x * 256 + threadIdx.x;      // 16384 = GG*OUTD
    int g = idx >> 7, o = idx & 127;
    float acc0 = 0.f, acc1 = 0.f, acc2 = 0.f, acc3 = 0.f;
#pragma unroll 4
    for (int d = 0; d < DD; d += 4) {
        float4 pv = *reinterpret_cast<const float4*>(&pooled[g * DD + d]);
        acc0 = fmaf(pv.x, Wf[(d + 0) * OUTD + o], acc0);
        acc1 = fmaf(pv.y, Wf[(d + 1) * OUTD + o], acc1);
        acc2 = fmaf(pv.z, Wf[(d + 2) * OUTD + o], acc2);
        acc3 = fmaf(pv.w, Wf[(d + 3) * OUTD + o], acc3);
    }
    float inv = 1.f / fmaxf((float)(gstart[g + 1] - gstart[g]), 1.f);
    out[g * OUTD + o] = (acc0 + acc1 + acc2 + acc3) * inv + bf[o];
}

// ---------------- launch ----------------

extern "C" void kernel_launch(void* const* d_in, const int* in_sizes, int n_in,
                              void* d_out, int out_size, void* d_ws, size_t ws_size,
                              hipStream_t stream) {
    const float* x     = (const float*)d_in[0];
    const int*   ei    = (const int*)d_in[1];
    const int*   batch = (const int*)d_in[2];
    const float* W[3]  = {(const float*)d_in[3], (const float*)d_in[9],  (const float*)d_in[15]};
    const float* As_[3] = {(const float*)d_in[4], (const float*)d_in[10], (const float*)d_in[16]};
    const float* Ad_[3] = {(const float*)d_in[5], (const float*)d_in[11], (const float*)d_in[17]};
    const float* Bi[3] = {(const float*)d_in[6], (const float*)d_in[12], (const float*)d_in[18]};
    const float* Ga[3] = {(const float*)d_in[7], (const float*)d_in[13], (const float*)d_in[19]};
    const float* Be[3] = {(const float*)d_in[8], (const float*)d_in[14], (const float*)d_in[20]};
    const float* fcW = (const float*)d_in[21];
    const float* fcb = (const float*)d_in[22];
    float* out = (float*)d_out;

    char* p = (char*)d_ws;
    auto carve = [&](size_t bytes) {
        char* r = p;
        p += (bytes + 255) & ~((size_t)255);
        return r;
    };
    unsigned short* xb0  = (unsigned short*)carve((size_t)MPAD * DD * 2);
    unsigned short* xb1  = (unsigned short*)carve((size_t)MPAD * DD * 2);
    unsigned short* hbuf = (unsigned short*)carve((size_t)MPAD * DD * 2);
    unsigned short* Wt   = (unsigned short*)carve((size_t)DD * DD * 2);
    float* es     = (float*)carve((size_t)NN * HH * 4);
    float* ed     = (float*)carve((size_t)NN * HH * 4);
    float* alpha  = (float*)carve((size_t)ETOT * HH * 4);
    float* invden = (float*)carve((size_t)NN * HH * 4);
    int*   deg    = (int*)carve((size_t)NN * 4);
    int*   rowptr = (int*)carve((size_t)(NN + 1) * 4);
    int*   wp     = (int*)carve((size_t)NN * 4);
    int*   csr    = (int*)carve((size_t)ETOT * 4);
    int*   gstart = (int*)carve((size_t)(GG + 1) * 4);
    float* pooled = (float*)carve((size_t)GG * DD * 4);

    // CSR build
    hipMemsetAsync(deg, 0, (size_t)NN * 4, stream);
    hipMemsetAsync(pooled, 0, (size_t)GG * DD * 4, stream);
    k_degree<<<(ETOT + 255) / 256, 256, 0, stream>>>(ei, deg);
    k_scan<<<1, 1024, 0, stream>>>(deg, rowptr);
    hipMemcpyAsync(wp, rowptr, (size_t)NN * 4, hipMemcpyDeviceToDevice, stream);
    k_scatter<<<(ETOT + 255) / 256, 256, 0, stream>>>(ei, wp, csr);
    k_gbounds<<<1, 256, 0, stream>>>(batch, gstart);

    // zero pad rows of xb1 (xb0's pad is zeroed by k_cast_x)
    hipMemsetAsync(xb1 + (size_t)NN * DD, 0, (size_t)(MPAD - NN) * DD * 2, stream);
    k_cast_x<<<(MPAD * DD / 4 + 255) / 256, 256, 0, stream>>>(x, xb0);

    unsigned short* xin = xb0;
    unsigned short* xnext = xb1;
    for (int l = 0; l < 3; l++) {
        k_wt<<<dim3(16, 16), dim3(32, 8), 0, stream>>>(W[l], Wt);
        k_gemm<<<dim3(MPAD / 128, 4), 256, 0, stream>>>(xin, Wt, hbuf);
        k_scores<<<(NN * HH) / 4, 256, 0, stream>>>(hbuf, As_[l], Ad_[l], es, ed);
        k_alpha<<<(NN * HH + 255) / 256, 256, 0, stream>>>(es, ed, rowptr, csr, alpha, invden);
        k_aggln<<<NN / 4, 256, 0, stream>>>(hbuf, alpha, invden, rowptr, csr,
                                            Bi[l], Ga[l], Be[l], xnext);
        unsigned short* t = xin; xin = xnext; xnext = t;
    }

    // after 3 swaps, final output is in xin
    k_pool1<<<dim3(GG, 8), 256, 0, stream>>>(xin, gstart, pooled);
    k_fc<<<(GG * OUTD) / 256, 256, 0, stream>>>(pooled, gstart, fcW, fcb, out);
}

// Round 14
// 456.267 us; speedup vs baseline: 1.1621x; 1.0451x over previous
//
#include <hip/hip_runtime.h>
#include <hip/hip_bf16.h>

#define NN 20000
#define MPAD 20096          // 157 * 128
#define EE 160000
#define ETOT 180000         // edges + self loops
#define HH 8
#define DD 512
#define CC 64
#define GG 128
#define OUTD 128

typedef __bf16 bf16x8 __attribute__((ext_vector_type(8)));
typedef unsigned short u16x8 __attribute__((ext_vector_type(8)));
typedef float f32x4 __attribute__((ext_vector_type(4)));

__device__ __forceinline__ float bf2f(unsigned short u) {
    unsigned int x = ((unsigned int)u) << 16;
    return __builtin_bit_cast(float, x);
}
__device__ __forceinline__ unsigned short f2bf(float f) {
    unsigned int x = __builtin_bit_cast(unsigned int, f);
    unsigned int r = (x + 0x7fff + ((x >> 16) & 1)) >> 16;
    return (unsigned short)r;
}

// ---------------- CSR build ----------------

__global__ void k_degree(const int* __restrict__ ei, int* __restrict__ deg) {
    int e = blockIdx.x * blockDim.x + threadIdx.x;
    if (e >= ETOT) return;
    int dst = (e < EE) ? ei[EE + e] : (e - EE);
    atomicAdd(&deg[dst], 1);
}

__global__ __launch_bounds__(1024) void k_scan(const int* __restrict__ deg,
                                               int* __restrict__ rowptr) {
    __shared__ int part[1024];
    const int n = NN;
    const int per = (n + 1023) / 1024;
    int base = threadIdx.x * per;
    int s = 0;
    for (int i = 0; i < per; i++) {
        int idx = base + i;
        if (idx < n) s += deg[idx];
    }
    part[threadIdx.x] = s;
    __syncthreads();
    for (int off = 1; off < 1024; off <<= 1) {
        int v = 0;
        if ((int)threadIdx.x >= off) v = part[threadIdx.x - off];
        __syncthreads();
        part[threadIdx.x] += v;
        __syncthreads();
    }
    int run = (threadIdx.x == 0) ? 0 : part[threadIdx.x - 1];
    for (int i = 0; i < per; i++) {
        int idx = base + i;
        if (idx < n) { rowptr[idx] = run; run += deg[idx]; }
    }
    if (threadIdx.x == 1023) rowptr[n] = part[1023];
}

__global__ void k_scatter(const int* __restrict__ ei, int* __restrict__ wp,
                          int* __restrict__ csr) {
    int e = blockIdx.x * blockDim.x + threadIdx.x;
    if (e >= ETOT) return;
    int src, dst;
    if (e < EE) { src = ei[e]; dst = ei[EE + e]; }
    else        { src = e - EE; dst = e - EE; }
    int pos = atomicAdd(&wp[dst], 1);
    csr[pos] = src;
}

// ---------------- f32 -> bf16 cast (with zero pad rows) ----------------

__global__ __launch_bounds__(256) void k_cast_x(const float* __restrict__ x,
                                                unsigned short* __restrict__ xb) {
    long long i = (long long)(blockIdx.x * 256 + threadIdx.x) * 4;
    if (i >= (long long)MPAD * DD) return;
    ushort4 o;
    if (i < (long long)NN * DD) {
        float4 v = *reinterpret_cast<const float4*>(&x[i]);
        o.x = f2bf(v.x); o.y = f2bf(v.y); o.z = f2bf(v.z); o.w = f2bf(v.w);
    } else {
        o = make_ushort4(0, 0, 0, 0);
    }
    *reinterpret_cast<ushort4*>(&xb[i]) = o;
}

// ---------------- W transpose + cast for all 3 layers: Wt[l][n][k] = bf16(W_l[k][n]) ----------------

__global__ __launch_bounds__(256) void k_wt3(const float* __restrict__ W0,
                                             const float* __restrict__ W1,
                                             const float* __restrict__ W2,
                                             unsigned short* __restrict__ Wt) {
    const float* W = (blockIdx.z == 0) ? W0 : (blockIdx.z == 1) ? W1 : W2;
    unsigned short* dst = Wt + (size_t)blockIdx.z * DD * DD;
    __shared__ float t[32][33];
    int tx = threadIdx.x, ty = threadIdx.y;
    int bk = blockIdx.x * 32, bn = blockIdx.y * 32;
#pragma unroll
    for (int j = 0; j < 4; j++)
        t[ty + j * 8][tx] = W[(bk + ty + j * 8) * DD + bn + tx];
    __syncthreads();
#pragma unroll
    for (int j = 0; j < 4; j++)
        dst[(bn + ty + j * 8) * DD + bk + tx] = f2bf(t[tx][ty + j * 8]);
}

// ---------------- bf16 MFMA GEMM (m97 structure, 128x128 tile, BK=32) ----------------

__global__ __launch_bounds__(256) void k_gemm(const unsigned short* __restrict__ A,
                                              const unsigned short* __restrict__ Bt,
                                              unsigned short* __restrict__ C) {
    __shared__ alignas(16) unsigned short As[128 * 32];
    __shared__ alignas(16) unsigned short Bs[128 * 32];
    int tid = threadIdx.x;
    int lane = tid & 63, wv = tid >> 6;
    int row0 = blockIdx.x * 128, col0 = blockIdx.y * 128;
    int wr = (wv >> 1) * 64, wc = (wv & 1) * 64;
    f32x4 acc[4][4] = {};
    int srow = lane >> 2;
    int sel = (lane & 3) * 8;

    for (int k0 = 0; k0 < DD; k0 += 32) {
#pragma unroll
        for (int i = 0; i < 2; i++) {
            int tr = wv * 32 + i * 16 + srow;
            __builtin_amdgcn_global_load_lds(
                (const __attribute__((address_space(1))) unsigned int*)&A[(size_t)(row0 + tr) * DD + k0 + sel],
                (__attribute__((address_space(3))) unsigned int*)&As[(wv * 32 + i * 16) * 32],
                16, 0, 0);
            __builtin_amdgcn_global_load_lds(
                (const __attribute__((address_space(1))) unsigned int*)&Bt[(size_t)(col0 + tr) * DD + k0 + sel],
                (__attribute__((address_space(3))) unsigned int*)&Bs[(wv * 32 + i * 16) * 32],
                16, 0, 0);
        }
        __syncthreads();
        bf16x8 af[4], bfv[4];
        int rsel = lane & 15, g = (lane >> 4) * 8;
#pragma unroll
        for (int m = 0; m < 4; m++)
            af[m] = *reinterpret_cast<const bf16x8*>(&As[(wr + m * 16 + rsel) * 32 + g]);
#pragma unroll
        for (int n2 = 0; n2 < 4; n2++)
            bfv[n2] = *reinterpret_cast<const bf16x8*>(&Bs[(wc + n2 * 16 + rsel) * 32 + g]);
#pragma unroll
        for (int m = 0; m < 4; m++)
#pragma unroll
            for (int n2 = 0; n2 < 4; n2++)
                acc[m][n2] = __builtin_amdgcn_mfma_f32_16x16x32_bf16(af[m], bfv[n2], acc[m][n2], 0, 0, 0);
        __syncthreads();
    }

    int crow = (lane >> 4) * 4, ccol = lane & 15;
#pragma unroll
    for (int m = 0; m < 4; m++) {
#pragma unroll
        for (int r = 0; r < 4; r++) {
            int row = row0 + wr + m * 16 + crow + r;
            if (row < NN) {
#pragma unroll
                for (int n2 = 0; n2 < 4; n2++)
                    C[(size_t)row * DD + col0 + wc + n2 * 16 + ccol] = f2bf(acc[m][n2][r]);
            }
        }
    }
}

// ---------------- attention scores ----------------

__global__ __launch_bounds__(256) void k_scores(const unsigned short* __restrict__ h,
                                                const float* __restrict__ a_s,
                                                const float* __restrict__ a_d,
                                                float* __restrict__ es,
                                                float* __restrict__ ed) {
    int wid = (blockIdx.x * 256 + threadIdx.x) >> 6;
    int lane = threadIdx.x & 63;
    if (wid >= NN * HH) return;
    int n = wid >> 3, hh = wid & 7;
    float v = bf2f(h[(size_t)n * DD + hh * CC + lane]);
    float ps = v * a_s[hh * CC + lane];
    float pd = v * a_d[hh * CC + lane];
#pragma unroll
    for (int off = 32; off > 0; off >>= 1) {
        ps += __shfl_down(ps, off);
        pd += __shfl_down(pd, off);
    }
    if (lane == 0) { es[wid] = ps; ed[wid] = pd; }
}

// ---------------- fused edge-softmax + gather + bias + LayerNorm + ReLU ----------------
// one wave per node; head = lane>>3; softmax max/sum via 8-lane-group shuffles; no LDS

__global__ __launch_bounds__(256) void k_aggln2(const unsigned short* __restrict__ h,
                                                const float* __restrict__ es,
                                                const float* __restrict__ ed,
                                                const int* __restrict__ rowptr,
                                                const int* __restrict__ csr,
                                                const float* __restrict__ bias,
                                                const float* __restrict__ gamma,
                                                const float* __restrict__ beta,
                                                unsigned short* __restrict__ xout) {
    int wv = threadIdx.x >> 6, lane = threadIdx.x & 63;
    int n = blockIdx.x * 4 + wv;
    int r0 = rowptr[n], r1 = rowptr[n + 1];
    int head = lane >> 3, sub = lane & 7;
    int d0 = lane * 8;
    float edn = ed[n * 8 + head];

    // phase 1: per-head max over edges (lanes of a head group stride the edge list)
    float m = -1e30f;
    for (int j = r0 + sub; j < r1; j += 8) {
        float e = es[csr[j] * 8 + head] + edn;
        e = (e >= 0.f) ? e : 0.2f * e;
        m = fmaxf(m, e);
    }
    m = fmaxf(m, __shfl_xor(m, 1));
    m = fmaxf(m, __shfl_xor(m, 2));
    m = fmaxf(m, __shfl_xor(m, 4));

    // phase 2: per-head sum of exp
    float s = 0.f;
    for (int j = r0 + sub; j < r1; j += 8) {
        float e = es[csr[j] * 8 + head] + edn;
        e = (e >= 0.f) ? e : 0.2f * e;
        s += __expf(e - m);
    }
    s += __shfl_xor(s, 1);
    s += __shfl_xor(s, 2);
    s += __shfl_xor(s, 4);
    float inv = 1.f / (s + 1e-16f);

    // phase 3: gather (recompute p per edge; es is L2-hot)
    float acc[8] = {};
    for (int j = r0; j < r1; j++) {
        int src = csr[j];
        float e = es[src * 8 + head] + edn;
        e = (e >= 0.f) ? e : 0.2f * e;
        float p = __expf(e - m);
        u16x8 hv = *reinterpret_cast<const u16x8*>(&h[(size_t)src * DD + d0]);
#pragma unroll
        for (int k = 0; k < 8; k++) acc[k] += p * bf2f(hv[k]);
    }

    float s1 = 0.f, s2 = 0.f;
#pragma unroll
    for (int k = 0; k < 8; k++) {
        acc[k] = acc[k] * inv + bias[d0 + k];
        s1 += acc[k];
        s2 += acc[k] * acc[k];
    }
#pragma unroll
    for (int off = 1; off < 64; off <<= 1) {
        s1 += __shfl_xor(s1, off);
        s2 += __shfl_xor(s2, off);
    }
    float mu = s1 * (1.f / 512.f);
    float var = s2 * (1.f / 512.f) - mu * mu;
    float rs = rsqrtf(var + 1e-5f);

    u16x8 o;
#pragma unroll
    for (int k = 0; k < 8; k++) {
        float y = (acc[k] - mu) * rs * gamma[d0 + k] + beta[d0 + k];
        o[k] = f2bf(fmaxf(y, 0.f));
    }
    *reinterpret_cast<u16x8*>(&xout[(size_t)n * DD + d0]) = o;
}

// ---------------- pooling + FC ----------------

__global__ void k_gbounds(const int* __restrict__ batch, int* __restrict__ gstart) {
    int g = blockIdx.x * blockDim.x + threadIdx.x;
    if (g > GG) return;
    int lo = 0, hi = NN;
    while (lo < hi) {
        int mid = (lo + hi) >> 1;
        if (batch[mid] < g) lo = mid + 1; else hi = mid;
    }
    gstart[g] = lo;
}

// parallel pooling: grid (GG, 8 node-stripes); partial sums in regs, one atomicAdd per dim
__global__ __launch_bounds__(256) void k_pool1(const unsigned short* __restrict__ x,
                                               const int* __restrict__ gstart,
                                               float* __restrict__ pooled) {
    int g = blockIdx.x, stripe = blockIdx.y, tid = threadIdx.x;
    int s = gstart[g], e = gstart[g + 1];
    float a0 = 0.f, a1 = 0.f;
    for (int n = s + stripe; n < e; n += 8) {
        unsigned int u = *reinterpret_cast<const unsigned int*>(&x[(size_t)n * DD + tid * 2]);
        a0 += bf2f((unsigned short)(u & 0xffff));
        a1 += bf2f((unsigned short)(u >> 16));
    }
    atomicAdd(&pooled[g * DD + tid * 2], a0);
    atomicAdd(&pooled[g * DD + tid * 2 + 1], a1);
}

// FC: one thread per (g, o) output; 4 independent FMA chains; mean-divide folded in
__global__ __launch_bounds__(256) void k_fc(const float* __restrict__ pooled,
                                            const int* __restrict__ gstart,
                                            const float* __restrict__ Wf,
                                            const float* __restrict__ bf,
                                            float* __restrict__ out) {
    int idx = blockIdx.x * 256 + threadIdx.x;      // 16384 = GG*OUTD
    int g = idx >> 7, o = idx & 127;
    float acc0 = 0.f, acc1 = 0.f, acc2 = 0.f, acc3 = 0.f;
#pragma unroll 4
    for (int d = 0; d < DD; d += 4) {
        float4 pv = *reinterpret_cast<const float4*>(&pooled[g * DD + d]);
        acc0 = fmaf(pv.x, Wf[(d + 0) * OUTD + o], acc0);
        acc1 = fmaf(pv.y, Wf[(d + 1) * OUTD + o], acc1);
        acc2 = fmaf(pv.z, Wf[(d + 2) * OUTD + o], acc2);
        acc3 = fmaf(pv.w, Wf[(d + 3) * OUTD + o], acc3);
    }
    float inv = 1.f / fmaxf((float)(gstart[g + 1] - gstart[g]), 1.f);
    out[g * OUTD + o] = (acc0 + acc1 + acc2 + acc3) * inv + bf[o];
}

// ---------------- launch ----------------

extern "C" void kernel_launch(void* const* d_in, const int* in_sizes, int n_in,
                              void* d_out, int out_size, void* d_ws, size_t ws_size,
                              hipStream_t stream) {
    const float* x     = (const float*)d_in[0];
    const int*   ei    = (const int*)d_in[1];
    const int*   batch = (const int*)d_in[2];
    const float* W[3]  = {(const float*)d_in[3], (const float*)d_in[9],  (const float*)d_in[15]};
    const float* As_[3] = {(const float*)d_in[4], (const float*)d_in[10], (const float*)d_in[16]};
    const float* Ad_[3] = {(const float*)d_in[5], (const float*)d_in[11], (const float*)d_in[17]};
    const float* Bi[3] = {(const float*)d_in[6], (const float*)d_in[12], (const float*)d_in[18]};
    const float* Ga[3] = {(const float*)d_in[7], (const float*)d_in[13], (const float*)d_in[19]};
    const float* Be[3] = {(const float*)d_in[8], (const float*)d_in[14], (const float*)d_in[20]};
    const float* fcW = (const float*)d_in[21];
    const float* fcb = (const float*)d_in[22];
    float* out = (float*)d_out;

    char* p = (char*)d_ws;
    auto carve = [&](size_t bytes) {
        char* r = p;
        p += (bytes + 255) & ~((size_t)255);
        return r;
    };
    unsigned short* xb0  = (unsigned short*)carve((size_t)MPAD * DD * 2);
    unsigned short* xb1  = (unsigned short*)carve((size_t)MPAD * DD * 2);
    unsigned short* hbuf = (unsigned short*)carve((size_t)MPAD * DD * 2);
    unsigned short* Wt   = (unsigned short*)carve((size_t)3 * DD * DD * 2);
    float* es     = (float*)carve((size_t)NN * HH * 4);
    float* ed     = (float*)carve((size_t)NN * HH * 4);
    int*   deg    = (int*)carve((size_t)NN * 4);
    int*   rowptr = (int*)carve((size_t)(NN + 1) * 4);
    int*   wp     = (int*)carve((size_t)NN * 4);
    int*   csr    = (int*)carve((size_t)ETOT * 4);
    int*   gstart = (int*)carve((size_t)(GG + 1) * 4);
    float* pooled = (float*)carve((size_t)GG * DD * 4);

    // CSR build + weight prep
    hipMemsetAsync(deg, 0, (size_t)NN * 4, stream);
    hipMemsetAsync(pooled, 0, (size_t)GG * DD * 4, stream);
    k_degree<<<(ETOT + 255) / 256, 256, 0, stream>>>(ei, deg);
    k_scan<<<1, 1024, 0, stream>>>(deg, rowptr);
    hipMemcpyAsync(wp, rowptr, (size_t)NN * 4, hipMemcpyDeviceToDevice, stream);
    k_scatter<<<(ETOT + 255) / 256, 256, 0, stream>>>(ei, wp, csr);
    k_gbounds<<<1, 256, 0, stream>>>(batch, gstart);
    k_wt3<<<dim3(16, 16, 3), dim3(32, 8), 0, stream>>>(W[0], W[1], W[2], Wt);

    // zero pad rows of xb1 (xb0's pad is zeroed by k_cast_x)
    hipMemsetAsync(xb1 + (size_t)NN * DD, 0, (size_t)(MPAD - NN) * DD * 2, stream);
    k_cast_x<<<(MPAD * DD / 4 + 255) / 256, 256, 0, stream>>>(x, xb0);

    unsigned short* xin = xb0;
    unsigned short* xnext = xb1;
    for (int l = 0; l < 3; l++) {
        k_gemm<<<dim3(MPAD / 128, 4), 256, 0, stream>>>(xin, Wt + (size_t)l * DD * DD, hbuf);
        k_scores<<<(NN * HH) / 4, 256, 0, stream>>>(hbuf, As_[l], Ad_[l], es, ed);
        k_aggln2<<<NN / 4, 256, 0, stream>>>(hbuf, es, ed, rowptr, csr,
                                             Bi[l], Ga[l], Be[l], xnext);
        unsigned short* t = xin; xin = xnext; xnext = t;
    }

    // after 3 swaps, final output is in xin
    k_pool1<<<dim3(GG, 8), 256, 0, stream>>>(xin, gstart, pooled);
    k_fc<<<(GG * OUTD) / 256, 256, 0, stream>>>(pooled, gstart, fcW, fcb, out);
}

// Round 15
// 409.993 us; speedup vs baseline: 1.2932x; 1.1129x over previous
//
#include <hip/hip_runtime.h>
#include <hip/hip_bf16.h>

#define NN 20000
#define MPAD 20096          // 157 * 128
#define EE 160000
#define ETOT 180000         // edges + self loops
#define HH 8
#define DD 512
#define CC 64
#define GG 128
#define OUTD 128

typedef __bf16 bf16x8 __attribute__((ext_vector_type(8)));
typedef unsigned short u16x8 __attribute__((ext_vector_type(8)));
typedef float f32x4 __attribute__((ext_vector_type(4)));

__device__ __forceinline__ float bf2f(unsigned short u) {
    unsigned int x = ((unsigned int)u) << 16;
    return __builtin_bit_cast(float, x);
}
__device__ __forceinline__ unsigned short f2bf(float f) {
    unsigned int x = __builtin_bit_cast(unsigned int, f);
    unsigned int r = (x + 0x7fff + ((x >> 16) & 1)) >> 16;
    return (unsigned short)r;
}

// ---------------- CSR build ----------------

__global__ void k_degree(const int* __restrict__ ei, int* __restrict__ deg) {
    int e = blockIdx.x * blockDim.x + threadIdx.x;
    if (e >= ETOT) return;
    int dst = (e < EE) ? ei[EE + e] : (e - EE);
    atomicAdd(&deg[dst], 1);
}

__global__ __launch_bounds__(1024) void k_scan(const int* __restrict__ deg,
                                               int* __restrict__ rowptr) {
    __shared__ int part[1024];
    const int n = NN;
    const int per = (n + 1023) / 1024;
    int base = threadIdx.x * per;
    int s = 0;
    for (int i = 0; i < per; i++) {
        int idx = base + i;
        if (idx < n) s += deg[idx];
    }
    part[threadIdx.x] = s;
    __syncthreads();
    for (int off = 1; off < 1024; off <<= 1) {
        int v = 0;
        if ((int)threadIdx.x >= off) v = part[threadIdx.x - off];
        __syncthreads();
        part[threadIdx.x] += v;
        __syncthreads();
    }
    int run = (threadIdx.x == 0) ? 0 : part[threadIdx.x - 1];
    for (int i = 0; i < per; i++) {
        int idx = base + i;
        if (idx < n) { rowptr[idx] = run; run += deg[idx]; }
    }
    if (threadIdx.x == 1023) rowptr[n] = part[1023];
}

__global__ void k_scatter(const int* __restrict__ ei, int* __restrict__ wp,
                          int* __restrict__ csr) {
    int e = blockIdx.x * blockDim.x + threadIdx.x;
    if (e >= ETOT) return;
    int src, dst;
    if (e < EE) { src = ei[e]; dst = ei[EE + e]; }
    else        { src = e - EE; dst = e - EE; }
    int pos = atomicAdd(&wp[dst], 1);
    csr[pos] = src;
}

// ---------------- f32 -> bf16 cast (with zero pad rows) ----------------

__global__ __launch_bounds__(256) void k_cast_x(const float* __restrict__ x,
                                                unsigned short* __restrict__ xb) {
    long long i = (long long)(blockIdx.x * 256 + threadIdx.x) * 4;
    if (i >= (long long)MPAD * DD) return;
    ushort4 o;
    if (i < (long long)NN * DD) {
        float4 v = *reinterpret_cast<const float4*>(&x[i]);
        o.x = f2bf(v.x); o.y = f2bf(v.y); o.z = f2bf(v.z); o.w = f2bf(v.w);
    } else {
        o = make_ushort4(0, 0, 0, 0);
    }
    *reinterpret_cast<ushort4*>(&xb[i]) = o;
}

// ---------------- W transpose + cast for all 3 layers: Wt[l][n][k] = bf16(W_l[k][n]) ----------------

__global__ __launch_bounds__(256) void k_wt3(const float* __restrict__ W0,
                                             const float* __restrict__ W1,
                                             const float* __restrict__ W2,
                                             unsigned short* __restrict__ Wt) {
    const float* W = (blockIdx.z == 0) ? W0 : (blockIdx.z == 1) ? W1 : W2;
    unsigned short* dst = Wt + (size_t)blockIdx.z * DD * DD;
    __shared__ float t[32][33];
    int tx = threadIdx.x, ty = threadIdx.y;
    int bk = blockIdx.x * 32, bn = blockIdx.y * 32;
#pragma unroll
    for (int j = 0; j < 4; j++)
        t[ty + j * 8][tx] = W[(bk + ty + j * 8) * DD + bn + tx];
    __syncthreads();
#pragma unroll
    for (int j = 0; j < 4; j++)
        dst[(bn + ty + j * 8) * DD + bk + tx] = f2bf(t[tx][ty + j * 8]);
}

// ---------------- bf16 MFMA GEMM + fused attention-score epilogue ----------------
// m97 structure (128x128 tile, BK=32). Each wave's 64x64 C fragment covers exactly
// one head (cols hid*64..+64), so es/ed = C . a_s/a_d computed from registers.

__global__ __launch_bounds__(256) void k_gemm(const unsigned short* __restrict__ A,
                                              const unsigned short* __restrict__ Bt,
                                              const float* __restrict__ a_s,
                                              const float* __restrict__ a_d,
                                              unsigned short* __restrict__ C,
                                              float* __restrict__ es,
                                              float* __restrict__ ed) {
    __shared__ alignas(16) unsigned short As[128 * 32];
    __shared__ alignas(16) unsigned short Bs[128 * 32];
    int tid = threadIdx.x;
    int lane = tid & 63, wv = tid >> 6;
    int row0 = blockIdx.x * 128, col0 = blockIdx.y * 128;
    int wr = (wv >> 1) * 64, wc = (wv & 1) * 64;
    f32x4 acc[4][4] = {};
    int srow = lane >> 2;
    int sel = (lane & 3) * 8;

    for (int k0 = 0; k0 < DD; k0 += 32) {
#pragma unroll
        for (int i = 0; i < 2; i++) {
            int tr = wv * 32 + i * 16 + srow;
            __builtin_amdgcn_global_load_lds(
                (const __attribute__((address_space(1))) unsigned int*)&A[(size_t)(row0 + tr) * DD + k0 + sel],
                (__attribute__((address_space(3))) unsigned int*)&As[(wv * 32 + i * 16) * 32],
                16, 0, 0);
            __builtin_amdgcn_global_load_lds(
                (const __attribute__((address_space(1))) unsigned int*)&Bt[(size_t)(col0 + tr) * DD + k0 + sel],
                (__attribute__((address_space(3))) unsigned int*)&Bs[(wv * 32 + i * 16) * 32],
                16, 0, 0);
        }
        __syncthreads();
        bf16x8 af[4], bfv[4];
        int rsel = lane & 15, g = (lane >> 4) * 8;
#pragma unroll
        for (int m = 0; m < 4; m++)
            af[m] = *reinterpret_cast<const bf16x8*>(&As[(wr + m * 16 + rsel) * 32 + g]);
#pragma unroll
        for (int n2 = 0; n2 < 4; n2++)
            bfv[n2] = *reinterpret_cast<const bf16x8*>(&Bs[(wc + n2 * 16 + rsel) * 32 + g]);
#pragma unroll
        for (int m = 0; m < 4; m++)
#pragma unroll
            for (int n2 = 0; n2 < 4; n2++)
                acc[m][n2] = __builtin_amdgcn_mfma_f32_16x16x32_bf16(af[m], bfv[n2], acc[m][n2], 0, 0, 0);
        __syncthreads();
    }

    int crow = (lane >> 4) * 4, ccol = lane & 15;

    // C write
#pragma unroll
    for (int m = 0; m < 4; m++) {
#pragma unroll
        for (int r = 0; r < 4; r++) {
            int row = row0 + wr + m * 16 + crow + r;
            if (row < NN) {
#pragma unroll
                for (int n2 = 0; n2 < 4; n2++)
                    C[(size_t)row * DD + col0 + wc + n2 * 16 + ccol] = f2bf(acc[m][n2][r]);
            }
        }
    }

    // fused attention scores: this wave's head
    int hid = (col0 >> 6) + (wv & 1);
    float asv[4], adv[4];
#pragma unroll
    for (int n2 = 0; n2 < 4; n2++) {
        asv[n2] = a_s[hid * CC + n2 * 16 + ccol];
        adv[n2] = a_d[hid * CC + n2 * 16 + ccol];
    }
#pragma unroll
    for (int m = 0; m < 4; m++) {
        float ps[4], pd[4];
#pragma unroll
        for (int r = 0; r < 4; r++) {
            ps[r] = acc[m][0][r] * asv[0] + acc[m][1][r] * asv[1]
                  + acc[m][2][r] * asv[2] + acc[m][3][r] * asv[3];
            pd[r] = acc[m][0][r] * adv[0] + acc[m][1][r] * adv[1]
                  + acc[m][2][r] * adv[2] + acc[m][3][r] * adv[3];
        }
#pragma unroll
        for (int off = 1; off < 16; off <<= 1) {
#pragma unroll
            for (int r = 0; r < 4; r++) {
                ps[r] += __shfl_xor(ps[r], off);
                pd[r] += __shfl_xor(pd[r], off);
            }
        }
        if ((lane & 15) == 0) {
            int rbase = row0 + wr + m * 16 + crow;
#pragma unroll
            for (int r = 0; r < 4; r++) {
                int row = rbase + r;
                if (row < NN) {
                    es[row * 8 + hid] = ps[r];
                    ed[row * 8 + hid] = pd[r];
                }
            }
        }
    }
}

// ---------------- fused edge-softmax + gather + bias + LayerNorm + ReLU ----------------
// one wave per node; head = lane>>3; softmax max/sum via 8-lane-group shuffles; no LDS

__global__ __launch_bounds__(256) void k_aggln2(const unsigned short* __restrict__ h,
                                                const float* __restrict__ es,
                                                const float* __restrict__ ed,
                                                const int* __restrict__ rowptr,
                                                const int* __restrict__ csr,
                                                const float* __restrict__ bias,
                                                const float* __restrict__ gamma,
                                                const float* __restrict__ beta,
                                                unsigned short* __restrict__ xout) {
    int wv = threadIdx.x >> 6, lane = threadIdx.x & 63;
    int n = blockIdx.x * 4 + wv;
    int r0 = rowptr[n], r1 = rowptr[n + 1];
    int head = lane >> 3, sub = lane & 7;
    int d0 = lane * 8;
    float edn = ed[n * 8 + head];

    // phase 1: per-head max over edges
    float m = -1e30f;
    for (int j = r0 + sub; j < r1; j += 8) {
        float e = es[csr[j] * 8 + head] + edn;
        e = (e >= 0.f) ? e : 0.2f * e;
        m = fmaxf(m, e);
    }
    m = fmaxf(m, __shfl_xor(m, 1));
    m = fmaxf(m, __shfl_xor(m, 2));
    m = fmaxf(m, __shfl_xor(m, 4));

    // phase 2: per-head sum of exp
    float s = 0.f;
    for (int j = r0 + sub; j < r1; j += 8) {
        float e = es[csr[j] * 8 + head] + edn;
        e = (e >= 0.f) ? e : 0.2f * e;
        s += __expf(e - m);
    }
    s += __shfl_xor(s, 1);
    s += __shfl_xor(s, 2);
    s += __shfl_xor(s, 4);
    float inv = 1.f / (s + 1e-16f);

    // phase 3: gather, 2-way unrolled (two independent load chains in flight)
    float acc[8] = {};
    int j = r0;
    for (; j + 1 < r1; j += 2) {
        int s0 = csr[j], s1 = csr[j + 1];
        float e0 = es[s0 * 8 + head] + edn;
        float e1 = es[s1 * 8 + head] + edn;
        u16x8 h0 = *reinterpret_cast<const u16x8*>(&h[(size_t)s0 * DD + d0]);
        u16x8 h1 = *reinterpret_cast<const u16x8*>(&h[(size_t)s1 * DD + d0]);
        e0 = (e0 >= 0.f) ? e0 : 0.2f * e0;
        e1 = (e1 >= 0.f) ? e1 : 0.2f * e1;
        float p0 = __expf(e0 - m);
        float p1 = __expf(e1 - m);
#pragma unroll
        for (int k = 0; k < 8; k++)
            acc[k] += p0 * bf2f(h0[k]) + p1 * bf2f(h1[k]);
    }
    if (j < r1) {
        int s0 = csr[j];
        float e0 = es[s0 * 8 + head] + edn;
        e0 = (e0 >= 0.f) ? e0 : 0.2f * e0;
        float p0 = __expf(e0 - m);
        u16x8 h0 = *reinterpret_cast<const u16x8*>(&h[(size_t)s0 * DD + d0]);
#pragma unroll
        for (int k = 0; k < 8; k++) acc[k] += p0 * bf2f(h0[k]);
    }

    float s1 = 0.f, s2 = 0.f;
#pragma unroll
    for (int k = 0; k < 8; k++) {
        acc[k] = acc[k] * inv + bias[d0 + k];
        s1 += acc[k];
        s2 += acc[k] * acc[k];
    }
#pragma unroll
    for (int off = 1; off < 64; off <<= 1) {
        s1 += __shfl_xor(s1, off);
        s2 += __shfl_xor(s2, off);
    }
    float mu = s1 * (1.f / 512.f);
    float var = s2 * (1.f / 512.f) - mu * mu;
    float rs = rsqrtf(var + 1e-5f);

    u16x8 o;
#pragma unroll
    for (int k = 0; k < 8; k++) {
        float y = (acc[k] - mu) * rs * gamma[d0 + k] + beta[d0 + k];
        o[k] = f2bf(fmaxf(y, 0.f));
    }
    *reinterpret_cast<u16x8*>(&xout[(size_t)n * DD + d0]) = o;
}

// ---------------- pooling + FC ----------------

__global__ void k_gbounds(const int* __restrict__ batch, int* __restrict__ gstart) {
    int g = blockIdx.x * blockDim.x + threadIdx.x;
    if (g > GG) return;
    int lo = 0, hi = NN;
    while (lo < hi) {
        int mid = (lo + hi) >> 1;
        if (batch[mid] < g) lo = mid + 1; else hi = mid;
    }
    gstart[g] = lo;
}

// parallel pooling: grid (GG, 8 node-stripes); partial sums in regs, one atomicAdd per dim
__global__ __launch_bounds__(256) void k_pool1(const unsigned short* __restrict__ x,
                                               const int* __restrict__ gstart,
                                               float* __restrict__ pooled) {
    int g = blockIdx.x, stripe = blockIdx.y, tid = threadIdx.x;
    int s = gstart[g], e = gstart[g + 1];
    float a0 = 0.f, a1 = 0.f;
    for (int n = s + stripe; n < e; n += 8) {
        unsigned int u = *reinterpret_cast<const unsigned int*>(&x[(size_t)n * DD + tid * 2]);
        a0 += bf2f((unsigned short)(u & 0xffff));
        a1 += bf2f((unsigned short)(u >> 16));
    }
    atomicAdd(&pooled[g * DD + tid * 2], a0);
    atomicAdd(&pooled[g * DD + tid * 2 + 1], a1);
}

// FC: one thread per (g, o) output; 4 independent FMA chains; mean-divide folded in
__global__ __launch_bounds__(256) void k_fc(const float* __restrict__ pooled,
                                            const int* __restrict__ gstart,
                                            const float* __restrict__ Wf,
                                            const float* __restrict__ bf,
                                            float* __restrict__ out) {
    int idx = blockIdx.x * 256 + threadIdx.x;      // 16384 = GG*OUTD
    int g = idx >> 7, o = idx & 127;
    float acc0 = 0.f, acc1 = 0.f, acc2 = 0.f, acc3 = 0.f;
#pragma unroll 4
    for (int d = 0; d < DD; d += 4) {
        float4 pv = *reinterpret_cast<const float4*>(&pooled[g * DD + d]);
        acc0 = fmaf(pv.x, Wf[(d + 0) * OUTD + o], acc0);
        acc1 = fmaf(pv.y, Wf[(d + 1) * OUTD + o], acc1);
        acc2 = fmaf(pv.z, Wf[(d + 2) * OUTD + o], acc2);
        acc3 = fmaf(pv.w, Wf[(d + 3) * OUTD + o], acc3);
    }
    float inv = 1.f / fmaxf((float)(gstart[g + 1] - gstart[g]), 1.f);
    out[g * OUTD + o] = (acc0 + acc1 + acc2 + acc3) * inv + bf[o];
}

// ---------------- launch ----------------

extern "C" void kernel_launch(void* const* d_in, const int* in_sizes, int n_in,
                              void* d_out, int out_size, void* d_ws, size_t ws_size,
                              hipStream_t stream) {
    const float* x     = (const float*)d_in[0];
    const int*   ei    = (const int*)d_in[1];
    const int*   batch = (const int*)d_in[2];
    const float* W[3]  = {(const float*)d_in[3], (const float*)d_in[9],  (const float*)d_in[15]};
    const float* As_[3] = {(const float*)d_in[4], (const float*)d_in[10], (const float*)d_in[16]};
    const float* Ad_[3] = {(const float*)d_in[5], (const float*)d_in[11], (const float*)d_in[17]};
    const float* Bi[3] = {(const float*)d_in[6], (const float*)d_in[12], (const float*)d_in[18]};
    const float* Ga[3] = {(const float*)d_in[7], (const float*)d_in[13], (const float*)d_in[19]};
    const float* Be[3] = {(const float*)d_in[8], (const float*)d_in[14], (const float*)d_in[20]};
    const float* fcW = (const float*)d_in[21];
    const float* fcb = (const float*)d_in[22];
    float* out = (float*)d_out;

    char* p = (char*)d_ws;
    auto carve = [&](size_t bytes) {
        char* r = p;
        p += (bytes + 255) & ~((size_t)255);
        return r;
    };
    unsigned short* xb0  = (unsigned short*)carve((size_t)MPAD * DD * 2);
    unsigned short* xb1  = (unsigned short*)carve((size_t)MPAD * DD * 2);
    unsigned short* hbuf = (unsigned short*)carve((size_t)MPAD * DD * 2);
    unsigned short* Wt   = (unsigned short*)carve((size_t)3 * DD * DD * 2);
    float* es     = (float*)carve((size_t)NN * HH * 4);
    float* ed     = (float*)carve((size_t)NN * HH * 4);
    int*   deg    = (int*)carve((size_t)NN * 4);
    int*   rowptr = (int*)carve((size_t)(NN + 1) * 4);
    int*   wp     = (int*)carve((size_t)NN * 4);
    int*   csr    = (int*)carve((size_t)ETOT * 4);
    int*   gstart = (int*)carve((size_t)(GG + 1) * 4);
    float* pooled = (float*)carve((size_t)GG * DD * 4);

    // CSR build + weight prep
    hipMemsetAsync(deg, 0, (size_t)NN * 4, stream);
    hipMemsetAsync(pooled, 0, (size_t)GG * DD * 4, stream);
    k_degree<<<(ETOT + 255) / 256, 256, 0, stream>>>(ei, deg);
    k_scan<<<1, 1024, 0, stream>>>(deg, rowptr);
    hipMemcpyAsync(wp, rowptr, (size_t)NN * 4, hipMemcpyDeviceToDevice, stream);
    k_scatter<<<(ETOT + 255) / 256, 256, 0, stream>>>(ei, wp, csr);
    k_gbounds<<<1, 256, 0, stream>>>(batch, gstart);
    k_wt3<<<dim3(16, 16, 3), dim3(32, 8), 0, stream>>>(W[0], W[1], W[2], Wt);

    // zero pad rows of xb1 (xb0's pad is zeroed by k_cast_x)
    hipMemsetAsync(xb1 + (size_t)NN * DD, 0, (size_t)(MPAD - NN) * DD * 2, stream);
    k_cast_x<<<(MPAD * DD / 4 + 255) / 256, 256, 0, stream>>>(x, xb0);

    unsigned short* xin = xb0;
    unsigned short* xnext = xb1;
    for (int l = 0; l < 3; l++) {
        k_gemm<<<dim3(MPAD / 128, 4), 256, 0, stream>>>(xin, Wt + (size_t)l * DD * DD,
                                                        As_[l], Ad_[l], hbuf, es, ed);
        k_aggln2<<<NN / 4, 256, 0, stream>>>(hbuf, es, ed, rowptr, csr,
                                             Bi[l], Ga[l], Be[l], xnext);
        unsigned short* t = xin; xin = xnext; xnext = t;
    }

    // after 3 swaps, final output is in xin
    k_pool1<<<dim3(GG, 8), 256, 0, stream>>>(xin, gstart, pooled);
    k_fc<<<(GG * OUTD) / 256, 256, 0, stream>>>(pooled, gstart, fcW, fcb, out);
}